// Round 8
// baseline (181.619 us; speedup 1.0000x reference)
//
#include <hip/hip_runtime.h>

// Problem constants (from reference setup_inputs)
#define BATCH 16
#define CIN   3
#define H     384
#define W     384
#define HW    (H * W)
#define HO    382
#define WO    382
#define OFFC  18
#define OOUT  3
#define KTAPS 9

// Padded HWC layout: 2-px zero halo reproduces OOB-mask semantics.
#define PAD   2
#define HP    (H + 2 * PAD)     // 388
#define WP    (W + 2 * PAD)     // 388

// Packed-weight region (floats):
//  [0..485]   pk_cw : k in 0..8, idx in 0..26 -> {cw[2k][idx], cw[2k+1][idx]}
//  [486..503] pk_cb : {conv_b[2k], conv_b[2k+1]}
//  [504..557] pk_dw : ck in 0..26 -> {dcn_w[0][ck], dcn_w[1][ck]}
//  [558..584] dw2   : dcn_w[2][ck]
//  [585..586] db01, [587] db2
#define WPK_FLOATS 588

#define NXCD 8
// 2 px per thread: pairs per row = 191; pairs per image = 382*191 = 72962.
#define PPROW 191
#define PPIMG (HO * PPROW)          // 72962
#define PBLK  286                   // ceil(72962 / 256)
#define NWG2  (BATCH * PBLK)        // 4576 = 8 * 572

typedef float vf2 __attribute__((ext_vector_type(2)));
typedef float vf4 __attribute__((ext_vector_type(4)));
struct F3 { float a, b, c; };

static __device__ __forceinline__ vf2 splat2(float s) { vf2 r; r.x = s; r.y = s; return r; }

// bf16 helpers (fallback path): RNE pack, cheap unpack.
static __device__ __forceinline__ unsigned f2bf(float f) {
    const unsigned u = __float_as_uint(f);
    return (u + 0x7fffu + ((u >> 16) & 1u)) >> 16;
}
static __device__ __forceinline__ float bf_lo(unsigned d) { return __uint_as_float(d << 16); }
static __device__ __forceinline__ float bf_hi(unsigned d) { return __uint_as_float(d & 0xffff0000u); }

// ---------------------------------------------------------------------------
// Weight packing, shared by both pack kernels (block (0,0) only).
static __device__ __forceinline__ void pack_weights(const float* __restrict__ conv_w,
                                                    const float* __restrict__ conv_b,
                                                    const float* __restrict__ dcn_w,
                                                    const float* __restrict__ dcn_b,
                                                    float* __restrict__ wpk)
{
    for (int i = threadIdx.x; i < WPK_FLOATS; i += 256) {
        float v;
        if (i < 486) {
            const int k    = i / 54;
            const int r    = i - k * 54;
            const int idx  = r >> 1;
            const int half = r & 1;
            v = conv_w[(2 * k + half) * 27 + idx];
        } else if (i < 504) {
            v = conv_b[i - 486];
        } else if (i < 558) {
            const int r    = i - 504;
            const int ck   = r >> 1;
            const int half = r & 1;
            v = dcn_w[half * 27 + ck];
        } else if (i < 585) {
            v = dcn_w[2 * 27 + (i - 558)];
        } else if (i < 587) {
            v = dcn_b[i - 585];
        } else {
            v = dcn_b[2];
        }
        wpk[i] = v;
    }
}

// ---------------------------------------------------------------------------
// PRIMARY pass 1: CHW fp32 -> padded HWC fp32x4 (16 B/px: c0,c1,c2,0).
// Round 8: post-swizzle the kernel is compute-bound (HBM 11%), so trade
// bytes for instructions — fp32 corners remove the entire bf16 unpack stage
// (~19% of per-px VALU cycles) and make gathers exact (absmax improves).
__global__ __launch_bounds__(256)
void pack_f32_kernel(const float* __restrict__ x,
                     const float* __restrict__ conv_w,
                     const float* __restrict__ conv_b,
                     const float* __restrict__ dcn_w,
                     const float* __restrict__ dcn_b,
                     vf4* __restrict__ xt,
                     float* __restrict__ wpk)
{
    const int b  = blockIdx.y;
    const int r2 = blockIdx.x * 256 + threadIdx.x;

    if (blockIdx.x == 0 && b == 0)
        pack_weights(conv_w, conv_b, dcn_w, dcn_b, wpk);

    if (r2 >= HP * WP) return;
    const int ry = r2 / WP;
    const int rx = r2 - ry * WP;
    const int yi = ry - PAD;
    const int xi = rx - PAD;
    vf4 v; v.x = 0.f; v.y = 0.f; v.z = 0.f; v.w = 0.f;
    if ((unsigned)yi < (unsigned)H && (unsigned)xi < (unsigned)W) {
        const float* xb = x + (size_t)b * (CIN * HW);
        const int p = yi * W + xi;
        v.x = xb[p];
        v.y = xb[HW + p];
        v.z = xb[2 * HW + p];
    }
    xt[(size_t)b * (HP * WP) + r2] = v;
}

// ---------------------------------------------------------------------------
// PRIMARY pass 2: 2 px/thread, fp32x4 gathers (r6 structure minus unpack).
__global__ __launch_bounds__(256, 4)
void deform_f32_kernel(const float* __restrict__ x,
                       const vf4* __restrict__ xt,
                       const float* __restrict__ wpk,
                       float* __restrict__ out)
{
    const int orig = blockIdx.x;
    const int wg   = (orig & (NXCD - 1)) * (NWG2 / NXCD) + (orig >> 3);

    const int b   = wg / PBLK;
    const int pbk = wg - b * PBLK;

    const int tp = pbk * 256 + threadIdx.x;
    if (tp >= PPIMG) return;
    const int ho  = tp / PPROW;
    const int wp_ = tp - ho * PPROW;
    const int wo0 = wp_ * 2;

    const vf2*   pk_cw = (const vf2*)wpk;
    const vf2*   pk_cb = (const vf2*)(wpk + 486);
    const vf2*   pk_dw = (const vf2*)(wpk + 504);
    const float* dw2   = wpk + 558;

    const float* xb  = x  + (size_t)b * (CIN * HW);
    const vf4*   xtb = xt + (size_t)b * (HP * WP);

    // Shared 3x4x3 fp32 patch from original CHW x.
    vf4 xq[CIN][3];
    #pragma unroll
    for (int c = 0; c < CIN; ++c) {
        const float* xc = xb + c * HW + ho * W + wo0;
        #pragma unroll
        for (int i = 0; i < 3; ++i)
            __builtin_memcpy(&xq[c][i], xc + i * W, 16);
    }

    // Offset conv for both pixels (fp32-exact, identical to r6).
    vf2 offA[KTAPS], offB[KTAPS];
    #pragma unroll
    for (int k = 0; k < KTAPS; ++k) {
        vf2 aA = pk_cb[k];
        vf2 aB = pk_cb[k];
        #pragma unroll
        for (int c = 0; c < CIN; ++c)
            #pragma unroll
            for (int i = 0; i < 3; ++i)
                #pragma unroll
                for (int j = 0; j < 3; ++j) {
                    const vf2 w = pk_cw[k * 27 + c * 9 + i * 3 + j];
                    aA = __builtin_elementwise_fma(w, splat2(xq[c][i][j]),     aA);
                    aB = __builtin_elementwise_fma(w, splat2(xq[c][i][j + 1]), aB);
                }
        offA[k] = aA;
        offB[k] = aB;
    }

    vf2   accA01 = *(const vf2*)(wpk + 585);
    float accA2  = wpk[587];
    vf2   accB01 = accA01;
    float accB2  = accA2;

    #pragma unroll
    for (int k = 0; k < KTAPS; ++k) {
        const int ky = k / 3;
        const int kx = k % 3;

        #pragma unroll
        for (int p = 0; p < 2; ++p) {
            const vf2 o = (p == 0) ? offA[k] : offB[k];
            vf2&   acc01 = (p == 0) ? accA01 : accB01;
            float& acc2  = (p == 0) ? accA2  : accB2;
            const int wo = wo0 + p;

            vf2 f;
            f.x = floorf(o.x);
            f.y = floorf(o.y);
            const vf2 w  = o - f;                // (wy, wx)
            const vf2 cw = splat2(1.f) - w;      // (cwy, cwx)

            int iy = (int)f.x + (ho + ky + PAD);
            int ix = (int)f.y + (wo + kx + PAD);
            iy = min(max(iy, 0), HP - 2);
            ix = min(max(ix, 0), WP - 2);

            const vf4* base2 = xtb + iy * WP + ix;
            const vf4 q00 = base2[0];
            const vf4 q01 = base2[1];
            const vf4 q10 = base2[WP];
            const vf4 q11 = base2[WP + 1];

            const float w00 = cw.x * cw.y;
            const float w01 = cw.x * w.y;
            const float w10 = w.x * cw.y;
            const float w11 = w.x * w.y;

            // Channels (0,1) as vf2 directly from the float4 — no unpack.
            vf2 c00; c00.x = q00.x; c00.y = q00.y;
            vf2 c01; c01.x = q01.x; c01.y = q01.y;
            vf2 c10; c10.x = q10.x; c10.y = q10.y;
            vf2 c11; c11.x = q11.x; c11.y = q11.y;
            vf2 s01 = c00 * splat2(w00);
            s01 = __builtin_elementwise_fma(c01, splat2(w01), s01);
            s01 = __builtin_elementwise_fma(c10, splat2(w10), s01);
            s01 = __builtin_elementwise_fma(c11, splat2(w11), s01);

            float s2 = q00.z * w00;
            s2 = fmaf(q01.z, w01, s2);
            s2 = fmaf(q10.z, w10, s2);
            s2 = fmaf(q11.z, w11, s2);

            acc01 = __builtin_elementwise_fma(pk_dw[0 * 9 + k], splat2(s01.x), acc01);
            acc01 = __builtin_elementwise_fma(pk_dw[1 * 9 + k], splat2(s01.y), acc01);
            acc01 = __builtin_elementwise_fma(pk_dw[2 * 9 + k], splat2(s2),    acc01);
            acc2 = fmaf(dw2[0 * 9 + k], s01.x, acc2);
            acc2 = fmaf(dw2[1 * 9 + k], s01.y, acc2);
            acc2 = fmaf(dw2[2 * 9 + k], s2,    acc2);
        }
    }

    const int obase = b * (OOUT * HO * WO) + ho * WO + wo0;
    vf2 st0; st0.x = accA01.x; st0.y = accB01.x;
    vf2 st1; st1.x = accA01.y; st1.y = accB01.y;
    vf2 st2; st2.x = accA2;    st2.y = accB2;
    __builtin_nontemporal_store(st0, (vf2*)(out + obase));
    __builtin_nontemporal_store(st1, (vf2*)(out + obase + HO * WO));
    __builtin_nontemporal_store(st2, (vf2*)(out + obase + 2 * HO * WO));
}

// ---------------------------------------------------------------------------
// FALLBACK pass 1 (bf16, 8 B/px) — r6 path, used when ws < 38.6 MB.
__global__ __launch_bounds__(256)
void pack_bf16_kernel(const float* __restrict__ x,
                      const float* __restrict__ conv_w,
                      const float* __restrict__ conv_b,
                      const float* __restrict__ dcn_w,
                      const float* __restrict__ dcn_b,
                      uint2* __restrict__ xt,
                      float* __restrict__ wpk)
{
    const int b  = blockIdx.y;
    const int r2 = blockIdx.x * 256 + threadIdx.x;

    if (blockIdx.x == 0 && b == 0)
        pack_weights(conv_w, conv_b, dcn_w, dcn_b, wpk);

    if (r2 >= HP * WP) return;
    const int ry = r2 / WP;
    const int rx = r2 - ry * WP;
    const int yi = ry - PAD;
    const int xi = rx - PAD;
    uint2 v = make_uint2(0u, 0u);
    if ((unsigned)yi < (unsigned)H && (unsigned)xi < (unsigned)W) {
        const float* xb = x + (size_t)b * (CIN * HW);
        const int p = yi * W + xi;
        v.x = f2bf(xb[p]) | (f2bf(xb[HW + p]) << 16);
        v.y = f2bf(xb[2 * HW + p]);
    }
    xt[(size_t)b * (HP * WP) + r2] = v;
}

// FALLBACK pass 2 (r6 bf16 deform, verbatim).
__global__ __launch_bounds__(256, 4)
void deform_bf16_kernel(const float* __restrict__ x,
                        const uint2* __restrict__ xt,
                        const float* __restrict__ wpk,
                        float* __restrict__ out)
{
    const int orig = blockIdx.x;
    const int wg   = (orig & (NXCD - 1)) * (NWG2 / NXCD) + (orig >> 3);

    const int b   = wg / PBLK;
    const int pbk = wg - b * PBLK;

    const int tp = pbk * 256 + threadIdx.x;
    if (tp >= PPIMG) return;
    const int ho  = tp / PPROW;
    const int wp_ = tp - ho * PPROW;
    const int wo0 = wp_ * 2;

    const vf2*   pk_cw = (const vf2*)wpk;
    const vf2*   pk_cb = (const vf2*)(wpk + 486);
    const vf2*   pk_dw = (const vf2*)(wpk + 504);
    const float* dw2   = wpk + 558;

    const float* xb  = x  + (size_t)b * (CIN * HW);
    const uint2* xtb = xt + (size_t)b * (HP * WP);

    vf4 xq[CIN][3];
    #pragma unroll
    for (int c = 0; c < CIN; ++c) {
        const float* xc = xb + c * HW + ho * W + wo0;
        #pragma unroll
        for (int i = 0; i < 3; ++i)
            __builtin_memcpy(&xq[c][i], xc + i * W, 16);
    }

    vf2 offA[KTAPS], offB[KTAPS];
    #pragma unroll
    for (int k = 0; k < KTAPS; ++k) {
        vf2 aA = pk_cb[k];
        vf2 aB = pk_cb[k];
        #pragma unroll
        for (int c = 0; c < CIN; ++c)
            #pragma unroll
            for (int i = 0; i < 3; ++i)
                #pragma unroll
                for (int j = 0; j < 3; ++j) {
                    const vf2 w = pk_cw[k * 27 + c * 9 + i * 3 + j];
                    aA = __builtin_elementwise_fma(w, splat2(xq[c][i][j]),     aA);
                    aB = __builtin_elementwise_fma(w, splat2(xq[c][i][j + 1]), aB);
                }
        offA[k] = aA;
        offB[k] = aB;
    }

    vf2   accA01 = *(const vf2*)(wpk + 585);
    float accA2  = wpk[587];
    vf2   accB01 = accA01;
    float accB2  = accA2;

    #pragma unroll
    for (int k = 0; k < KTAPS; ++k) {
        const int ky = k / 3;
        const int kx = k % 3;

        #pragma unroll
        for (int p = 0; p < 2; ++p) {
            const vf2 o = (p == 0) ? offA[k] : offB[k];
            vf2&   acc01 = (p == 0) ? accA01 : accB01;
            float& acc2  = (p == 0) ? accA2  : accB2;
            const int wo = wo0 + p;

            vf2 f;
            f.x = floorf(o.x);
            f.y = floorf(o.y);
            const vf2 w  = o - f;
            const vf2 cw = splat2(1.f) - w;

            int iy = (int)f.x + (ho + ky + PAD);
            int ix = (int)f.y + (wo + kx + PAD);
            iy = min(max(iy, 0), HP - 2);
            ix = min(max(ix, 0), WP - 2);

            const uint2* base2 = xtb + iy * WP + ix;
            const uint2 q00 = base2[0];
            const uint2 q01 = base2[1];
            const uint2 q10 = base2[WP];
            const uint2 q11 = base2[WP + 1];

            const float w00 = cw.x * cw.y;
            const float w01 = cw.x * w.y;
            const float w10 = w.x * cw.y;
            const float w11 = w.x * w.y;

            vf2 c00, c01, c10, c11;
            c00.x = bf_lo(q00.x); c00.y = bf_hi(q00.x);
            c01.x = bf_lo(q01.x); c01.y = bf_hi(q01.x);
            c10.x = bf_lo(q10.x); c10.y = bf_hi(q10.x);
            c11.x = bf_lo(q11.x); c11.y = bf_hi(q11.x);
            vf2 s01 = c00 * splat2(w00);
            s01 = __builtin_elementwise_fma(c01, splat2(w01), s01);
            s01 = __builtin_elementwise_fma(c10, splat2(w10), s01);
            s01 = __builtin_elementwise_fma(c11, splat2(w11), s01);

            float s2 = bf_lo(q00.y) * w00;
            s2 = fmaf(bf_lo(q01.y), w01, s2);
            s2 = fmaf(bf_lo(q10.y), w10, s2);
            s2 = fmaf(bf_lo(q11.y), w11, s2);

            acc01 = __builtin_elementwise_fma(pk_dw[0 * 9 + k], splat2(s01.x), acc01);
            acc01 = __builtin_elementwise_fma(pk_dw[1 * 9 + k], splat2(s01.y), acc01);
            acc01 = __builtin_elementwise_fma(pk_dw[2 * 9 + k], splat2(s2),    acc01);
            acc2 = fmaf(dw2[0 * 9 + k], s01.x, acc2);
            acc2 = fmaf(dw2[1 * 9 + k], s01.y, acc2);
            acc2 = fmaf(dw2[2 * 9 + k], s2,    acc2);
        }
    }

    const int obase = b * (OOUT * HO * WO) + ho * WO + wo0;
    vf2 st0; st0.x = accA01.x; st0.y = accB01.x;
    vf2 st1; st1.x = accA01.y; st1.y = accB01.y;
    vf2 st2; st2.x = accA2;    st2.y = accB2;
    __builtin_nontemporal_store(st0, (vf2*)(out + obase));
    __builtin_nontemporal_store(st1, (vf2*)(out + obase + HO * WO));
    __builtin_nontemporal_store(st2, (vf2*)(out + obase + 2 * HO * WO));
}

// ---------------------------------------------------------------------------
// Fallback B (tiny ws): fused kernel, no workspace.
__global__ __launch_bounds__(256)
void deform_fused_kernel(const float* __restrict__ x,
                         const float* __restrict__ conv_w,
                         const float* __restrict__ conv_b,
                         const float* __restrict__ dcn_w,
                         const float* __restrict__ dcn_b,
                         float* __restrict__ out)
{
    __shared__ float s_cw[OFFC * 27];
    __shared__ float s_cb[OFFC];
    __shared__ float s_dw[OOUT * 27];
    __shared__ float s_db[OOUT];

    const int t = threadIdx.x;
    for (int i = t; i < OFFC * 27; i += 256) s_cw[i] = conv_w[i];
    if (t < OFFC)      s_cb[t] = conv_b[t];
    if (t < OOUT * 27) s_dw[t] = dcn_w[t];
    if (t < OOUT)      s_db[t] = dcn_b[t];
    __syncthreads();

    const int total = BATCH * HO * WO;
    const int gid = blockIdx.x * 256 + t;
    if (gid >= total) return;

    const int wo  = gid % WO;
    const int tmp = gid / WO;
    const int ho  = tmp % HO;
    const int b   = tmp / HO;

    const float* xb = x + b * (CIN * HW);

    float xp[CIN][3][3];
    #pragma unroll
    for (int c = 0; c < CIN; ++c) {
        const float* xc = xb + c * HW + ho * W + wo;
        #pragma unroll
        for (int i = 0; i < 3; ++i)
            #pragma unroll
            for (int j = 0; j < 3; ++j)
                xp[c][i][j] = xc[i * W + j];
    }

    float off[OFFC];
    #pragma unroll
    for (int o = 0; o < OFFC; ++o) {
        float a = s_cb[o];
        const float* wv = &s_cw[o * 27];
        #pragma unroll
        for (int c = 0; c < CIN; ++c)
            #pragma unroll
            for (int i = 0; i < 3; ++i)
                #pragma unroll
                for (int j = 0; j < 3; ++j)
                    a = fmaf(wv[c * 9 + i * 3 + j], xp[c][i][j], a);
        off[o] = a;
    }

    float a0 = s_db[0], a1 = s_db[1], a2 = s_db[2];

    #pragma unroll
    for (int k = 0; k < KTAPS; ++k) {
        const int ky = k / 3;
        const int kx = k % 3;
        const float py = off[2 * k]     + (float)(ho + ky);
        const float px = off[2 * k + 1] + (float)(wo + kx);
        const float y0f = floorf(py);
        const float x0f = floorf(px);
        const float wy = py - y0f;
        const float wx = px - x0f;
        const int y0 = (int)y0f;
        const int x0 = (int)x0f;
        const int y1 = y0 + 1;
        const int x1 = x0 + 1;
        const bool vy0 = (unsigned)y0 < (unsigned)H;
        const bool vy1 = (unsigned)y1 < (unsigned)H;
        const bool vx0 = (unsigned)x0 < (unsigned)W;
        const bool vx1 = (unsigned)x1 < (unsigned)W;
        const int cy0 = min(max(y0, 0), H - 1);
        const int cy1 = min(max(y1, 0), H - 1);
        const int cx0 = min(max(x0, 0), W - 1);
        const int cx1 = min(max(x1, 0), W - 1);
        const float w00 = (vy0 && vx0) ? (1.f - wy) * (1.f - wx) : 0.f;
        const float w01 = (vy0 && vx1) ? (1.f - wy) * wx         : 0.f;
        const float w10 = (vy1 && vx0) ? wy * (1.f - wx)         : 0.f;
        const float w11 = (vy1 && vx1) ? wy * wx                 : 0.f;
        const int i00 = cy0 * W + cx0;
        const int i01 = cy0 * W + cx1;
        const int i10 = cy1 * W + cx0;
        const int i11 = cy1 * W + cx1;
        #pragma unroll
        for (int c = 0; c < CIN; ++c) {
            const float* xc = xb + c * HW;
            float s = xc[i00] * w00;
            s = fmaf(xc[i01], w01, s);
            s = fmaf(xc[i10], w10, s);
            s = fmaf(xc[i11], w11, s);
            a0 = fmaf(s_dw[0 * 27 + c * 9 + k], s, a0);
            a1 = fmaf(s_dw[1 * 27 + c * 9 + k], s, a1);
            a2 = fmaf(s_dw[2 * 27 + c * 9 + k], s, a2);
        }
    }

    const int obase = b * (OOUT * HO * WO) + ho * WO + wo;
    __builtin_nontemporal_store(a0, out + obase);
    __builtin_nontemporal_store(a1, out + obase + HO * WO);
    __builtin_nontemporal_store(a2, out + obase + 2 * HO * WO);
}

extern "C" void kernel_launch(void* const* d_in, const int* in_sizes, int n_in,
                              void* d_out, int out_size, void* d_ws, size_t ws_size,
                              hipStream_t stream) {
    const float* x      = (const float*)d_in[0];
    const float* conv_w = (const float*)d_in[1];
    const float* conv_b = (const float*)d_in[2];
    const float* dcn_w  = (const float*)d_in[3];
    const float* dcn_b  = (const float*)d_in[4];
    float* out = (float*)d_out;

    const int total = BATCH * HO * WO;
    const size_t xt4_bytes = (size_t)BATCH * HP * WP * sizeof(vf4);    // 38.5 MB
    const size_t need_f32  = xt4_bytes + WPK_FLOATS * sizeof(float);
    const size_t xt_bytes  = (size_t)BATCH * HP * WP * sizeof(uint2);  // 19.3 MB
    const size_t need_bf   = xt_bytes + WPK_FLOATS * sizeof(float);

    if (ws_size >= need_f32) {
        vf4* xt = (vf4*)d_ws;
        float* wpk = (float*)((char*)d_ws + xt4_bytes);
        dim3 pack_grid((HP * WP + 255) / 256, BATCH);
        pack_f32_kernel<<<pack_grid, 256, 0, stream>>>(
            x, conv_w, conv_b, dcn_w, dcn_b, xt, wpk);
        deform_f32_kernel<<<NWG2, 256, 0, stream>>>(x, xt, wpk, out);
    } else if (ws_size >= need_bf) {
        uint2* xt = (uint2*)d_ws;
        float* wpk = (float*)((char*)d_ws + xt_bytes);
        dim3 pack_grid((HP * WP + 255) / 256, BATCH);
        pack_bf16_kernel<<<pack_grid, 256, 0, stream>>>(
            x, conv_w, conv_b, dcn_w, dcn_b, xt, wpk);
        deform_bf16_kernel<<<NWG2, 256, 0, stream>>>(x, xt, wpk, out);
    } else {
        deform_fused_kernel<<<(total + 255) / 256, 256, 0, stream>>>(
            x, conv_w, conv_b, dcn_w, dcn_b, out);
    }
}

// Round 9
// 138.336 us; speedup vs baseline: 1.3129x; 1.3129x over previous
//
#include <hip/hip_runtime.h>

// Problem constants (from reference setup_inputs)
#define BATCH 16
#define CIN   3
#define H     384
#define W     384
#define HW    (H * W)
#define HO    382
#define WO    382
#define OFFC  18
#define OOUT  3
#define KTAPS 9

// Padded HWC layout: 2-px zero halo reproduces OOB-mask semantics.
#define PAD   2
#define HP    (H + 2 * PAD)     // 388
#define WP    (W + 2 * PAD)     // 388

// Packed-weight region (floats):
//  [0..485]   pk_cw : k in 0..8, idx in 0..26 -> {cw[2k][idx], cw[2k+1][idx]}
//  [486..503] pk_cb : {conv_b[2k], conv_b[2k+1]}
//  [504..557] pk_dw : ck in 0..26 -> {dcn_w[0][ck], dcn_w[1][ck]}
//  [558..584] dw2   : dcn_w[2][ck]
//  [585..586] db01, [587] db2
#define WPK_FLOATS 588

#define NXCD 8
// 2 px per thread: pairs per row = 191; pairs per image = 382*191 = 72962.
#define PPROW 191
#define PPIMG (HO * PPROW)          // 72962
#define PBLK  286                   // ceil(72962 / 256)
#define NWG2  (BATCH * PBLK)        // 4576 = 8 * 572

typedef float vf2 __attribute__((ext_vector_type(2)));
typedef float vf4 __attribute__((ext_vector_type(4)));
struct F3 { float a, b, c; };

static __device__ __forceinline__ vf2 splat2(float s) { vf2 r; r.x = s; r.y = s; return r; }

// bf16 helpers: RNE pack, cheap unpack (bf16<<16 IS the fp32).
static __device__ __forceinline__ unsigned f2bf(float f) {
    const unsigned u = __float_as_uint(f);
    return (u + 0x7fffu + ((u >> 16) & 1u)) >> 16;
}
static __device__ __forceinline__ float bf_lo(unsigned d) { return __uint_as_float(d << 16); }
static __device__ __forceinline__ float bf_hi(unsigned d) { return __uint_as_float(d & 0xffff0000u); }

// ---------------------------------------------------------------------------
// Weight packing (block (0,0) only).
static __device__ __forceinline__ void pack_weights(const float* __restrict__ conv_w,
                                                    const float* __restrict__ conv_b,
                                                    const float* __restrict__ dcn_w,
                                                    const float* __restrict__ dcn_b,
                                                    float* __restrict__ wpk)
{
    for (int i = threadIdx.x; i < WPK_FLOATS; i += 256) {
        float v;
        if (i < 486) {
            const int k    = i / 54;
            const int r    = i - k * 54;
            const int idx  = r >> 1;
            const int half = r & 1;
            v = conv_w[(2 * k + half) * 27 + idx];
        } else if (i < 504) {
            v = conv_b[i - 486];
        } else if (i < 558) {
            const int r    = i - 504;
            const int ck   = r >> 1;
            const int half = r & 1;
            v = dcn_w[half * 27 + ck];
        } else if (i < 585) {
            v = dcn_w[2 * 27 + (i - 558)];
        } else if (i < 587) {
            v = dcn_b[i - 585];
        } else {
            v = dcn_b[2];
        }
        wpk[i] = v;
    }
}

// ---------------------------------------------------------------------------
// Pass 1: CHW fp32 -> padded HWC bf16x4 (8 B/px) + weight packing.
// bf16 8 B/px is LOAD-BEARING: round 8 proved fp32x4 (16 B/px) blows the
// per-XCD L2 (FETCH 23->59 MB, 4x write amplification, deform 61->103 us).
__global__ __launch_bounds__(256)
void pack_bf16_kernel(const float* __restrict__ x,
                      const float* __restrict__ conv_w,
                      const float* __restrict__ conv_b,
                      const float* __restrict__ dcn_w,
                      const float* __restrict__ dcn_b,
                      uint2* __restrict__ xt,
                      float* __restrict__ wpk)
{
    const int b  = blockIdx.y;
    const int r2 = blockIdx.x * 256 + threadIdx.x;

    if (blockIdx.x == 0 && b == 0)
        pack_weights(conv_w, conv_b, dcn_w, dcn_b, wpk);

    if (r2 >= HP * WP) return;
    const int ry = r2 / WP;
    const int rx = r2 - ry * WP;
    const int yi = ry - PAD;
    const int xi = rx - PAD;
    uint2 v = make_uint2(0u, 0u);
    if ((unsigned)yi < (unsigned)H && (unsigned)xi < (unsigned)W) {
        const float* xb = x + (size_t)b * (CIN * HW);
        const int p = yi * W + xi;
        v.x = f2bf(xb[p]) | (f2bf(xb[HW + p]) << 16);
        v.y = f2bf(xb[2 * HW + p]);
    }
    xt[(size_t)b * (HP * WP) + r2] = v;
}

// ---------------------------------------------------------------------------
// Pass 2: 2 px/thread (r6 structure, best verified: 60.7 us).
//  - XCD-chunk swizzle (r2): FETCH 96 -> 23 MB.
//  - Block-uniform batch (r4): SGPR bases.
//  - Shared dwordx4 patch rows + paired stores (r6).
//  - Round 9: each tap's 2x2 corner fetch is TWO 16 B loads instead of four
//    8 B loads (base2[0..1] and base2[WP..WP+1] are contiguous, 8 B-aligned).
//    Same bytes, same values, bit-identical math — half the VMEM issue slots
//    and vmcnt tracking entries, so more taps' loads fit in flight.
__global__ __launch_bounds__(256, 4)
void deform_bf16_kernel(const float* __restrict__ x,
                        const uint2* __restrict__ xt,
                        const float* __restrict__ wpk,
                        float* __restrict__ out)
{
    const int orig = blockIdx.x;
    const int wg   = (orig & (NXCD - 1)) * (NWG2 / NXCD) + (orig >> 3);

    const int b   = wg / PBLK;
    const int pbk = wg - b * PBLK;

    const int tp = pbk * 256 + threadIdx.x;
    if (tp >= PPIMG) return;
    const int ho  = tp / PPROW;
    const int wp_ = tp - ho * PPROW;
    const int wo0 = wp_ * 2;

    const vf2*   pk_cw = (const vf2*)wpk;
    const vf2*   pk_cb = (const vf2*)(wpk + 486);
    const vf2*   pk_dw = (const vf2*)(wpk + 504);
    const float* dw2   = wpk + 558;

    const float* xb  = x  + (size_t)b * (CIN * HW);
    const uint2* xtb = xt + (size_t)b * (HP * WP);

    // Shared 3x4x3 fp32 patch from original CHW x.
    vf4 xq[CIN][3];
    #pragma unroll
    for (int c = 0; c < CIN; ++c) {
        const float* xc = xb + c * HW + ho * W + wo0;
        #pragma unroll
        for (int i = 0; i < 3; ++i)
            __builtin_memcpy(&xq[c][i], xc + i * W, 16);
    }

    // Offset conv for both pixels (fp32-exact, identical to r6).
    vf2 offA[KTAPS], offB[KTAPS];
    #pragma unroll
    for (int k = 0; k < KTAPS; ++k) {
        vf2 aA = pk_cb[k];
        vf2 aB = pk_cb[k];
        #pragma unroll
        for (int c = 0; c < CIN; ++c)
            #pragma unroll
            for (int i = 0; i < 3; ++i)
                #pragma unroll
                for (int j = 0; j < 3; ++j) {
                    const vf2 w = pk_cw[k * 27 + c * 9 + i * 3 + j];
                    aA = __builtin_elementwise_fma(w, splat2(xq[c][i][j]),     aA);
                    aB = __builtin_elementwise_fma(w, splat2(xq[c][i][j + 1]), aB);
                }
        offA[k] = aA;
        offB[k] = aB;
    }

    vf2   accA01 = *(const vf2*)(wpk + 585);
    float accA2  = wpk[587];
    vf2   accB01 = accA01;
    float accB2  = accA2;

    #pragma unroll
    for (int k = 0; k < KTAPS; ++k) {
        const int ky = k / 3;
        const int kx = k % 3;

        #pragma unroll
        for (int p = 0; p < 2; ++p) {
            const vf2 o = (p == 0) ? offA[k] : offB[k];
            vf2&   acc01 = (p == 0) ? accA01 : accB01;
            float& acc2  = (p == 0) ? accA2  : accB2;
            const int wo = wo0 + p;

            vf2 f;
            f.x = floorf(o.x);
            f.y = floorf(o.y);
            const vf2 w  = o - f;                // (wy, wx)
            const vf2 cw = splat2(1.f) - w;      // (cwy, cwx)

            int iy = (int)f.x + (ho + ky + PAD);
            int ix = (int)f.y + (wo + kx + PAD);
            iy = min(max(iy, 0), HP - 2);
            ix = min(max(ix, 0), WP - 2);

            const uint2* base2 = xtb + iy * WP + ix;

            // Two 16 B spans (8 B-aligned, unaligned-16B loads are fine on
            // gfx950): {q00,q01} and {q10,q11}. Same bytes as four 8 B loads.
            uint4 qtop, qbot;
            __builtin_memcpy(&qtop, base2, 16);
            __builtin_memcpy(&qbot, base2 + WP, 16);

            const float w00 = cw.x * cw.y;
            const float w01 = cw.x * w.y;
            const float w10 = w.x * cw.y;
            const float w11 = w.x * w.y;

            // Channels (0,1) packed in .x/.z words; channel 2 in .y/.w words.
            vf2 c00, c01, c10, c11;
            c00.x = bf_lo(qtop.x); c00.y = bf_hi(qtop.x);
            c01.x = bf_lo(qtop.z); c01.y = bf_hi(qtop.z);
            c10.x = bf_lo(qbot.x); c10.y = bf_hi(qbot.x);
            c11.x = bf_lo(qbot.z); c11.y = bf_hi(qbot.z);
            vf2 s01 = c00 * splat2(w00);
            s01 = __builtin_elementwise_fma(c01, splat2(w01), s01);
            s01 = __builtin_elementwise_fma(c10, splat2(w10), s01);
            s01 = __builtin_elementwise_fma(c11, splat2(w11), s01);

            float s2 = bf_lo(qtop.y) * w00;
            s2 = fmaf(bf_lo(qtop.w), w01, s2);
            s2 = fmaf(bf_lo(qbot.y), w10, s2);
            s2 = fmaf(bf_lo(qbot.w), w11, s2);

            acc01 = __builtin_elementwise_fma(pk_dw[0 * 9 + k], splat2(s01.x), acc01);
            acc01 = __builtin_elementwise_fma(pk_dw[1 * 9 + k], splat2(s01.y), acc01);
            acc01 = __builtin_elementwise_fma(pk_dw[2 * 9 + k], splat2(s2),    acc01);
            acc2 = fmaf(dw2[0 * 9 + k], s01.x, acc2);
            acc2 = fmaf(dw2[1 * 9 + k], s01.y, acc2);
            acc2 = fmaf(dw2[2 * 9 + k], s2,    acc2);
        }
    }

    const int obase = b * (OOUT * HO * WO) + ho * WO + wo0;
    vf2 st0; st0.x = accA01.x; st0.y = accB01.x;
    vf2 st1; st1.x = accA01.y; st1.y = accB01.y;
    vf2 st2; st2.x = accA2;    st2.y = accB2;
    __builtin_nontemporal_store(st0, (vf2*)(out + obase));
    __builtin_nontemporal_store(st1, (vf2*)(out + obase + HO * WO));
    __builtin_nontemporal_store(st2, (vf2*)(out + obase + 2 * HO * WO));
}

// ---------------------------------------------------------------------------
// Fallback (tiny ws): fused kernel, no workspace.
__global__ __launch_bounds__(256)
void deform_fused_kernel(const float* __restrict__ x,
                         const float* __restrict__ conv_w,
                         const float* __restrict__ conv_b,
                         const float* __restrict__ dcn_w,
                         const float* __restrict__ dcn_b,
                         float* __restrict__ out)
{
    __shared__ float s_cw[OFFC * 27];
    __shared__ float s_cb[OFFC];
    __shared__ float s_dw[OOUT * 27];
    __shared__ float s_db[OOUT];

    const int t = threadIdx.x;
    for (int i = t; i < OFFC * 27; i += 256) s_cw[i] = conv_w[i];
    if (t < OFFC)      s_cb[t] = conv_b[t];
    if (t < OOUT * 27) s_dw[t] = dcn_w[t];
    if (t < OOUT)      s_db[t] = dcn_b[t];
    __syncthreads();

    const int total = BATCH * HO * WO;
    const int gid = blockIdx.x * 256 + t;
    if (gid >= total) return;

    const int wo  = gid % WO;
    const int tmp = gid / WO;
    const int ho  = tmp % HO;
    const int b   = tmp / HO;

    const float* xb = x + b * (CIN * HW);

    float xp[CIN][3][3];
    #pragma unroll
    for (int c = 0; c < CIN; ++c) {
        const float* xc = xb + c * HW + ho * W + wo;
        #pragma unroll
        for (int i = 0; i < 3; ++i)
            #pragma unroll
            for (int j = 0; j < 3; ++j)
                xp[c][i][j] = xc[i * W + j];
    }

    float off[OFFC];
    #pragma unroll
    for (int o = 0; o < OFFC; ++o) {
        float a = s_cb[o];
        const float* wv = &s_cw[o * 27];
        #pragma unroll
        for (int c = 0; c < CIN; ++c)
            #pragma unroll
            for (int i = 0; i < 3; ++i)
                #pragma unroll
                for (int j = 0; j < 3; ++j)
                    a = fmaf(wv[c * 9 + i * 3 + j], xp[c][i][j], a);
        off[o] = a;
    }

    float a0 = s_db[0], a1 = s_db[1], a2 = s_db[2];

    #pragma unroll
    for (int k = 0; k < KTAPS; ++k) {
        const int ky = k / 3;
        const int kx = k % 3;
        const float py = off[2 * k]     + (float)(ho + ky);
        const float px = off[2 * k + 1] + (float)(wo + kx);
        const float y0f = floorf(py);
        const float x0f = floorf(px);
        const float wy = py - y0f;
        const float wx = px - x0f;
        const int y0 = (int)y0f;
        const int x0 = (int)x0f;
        const int y1 = y0 + 1;
        const int x1 = x0 + 1;
        const bool vy0 = (unsigned)y0 < (unsigned)H;
        const bool vy1 = (unsigned)y1 < (unsigned)H;
        const bool vx0 = (unsigned)x0 < (unsigned)W;
        const bool vx1 = (unsigned)x1 < (unsigned)W;
        const int cy0 = min(max(y0, 0), H - 1);
        const int cy1 = min(max(y1, 0), H - 1);
        const int cx0 = min(max(x0, 0), W - 1);
        const int cx1 = min(max(x1, 0), W - 1);
        const float w00 = (vy0 && vx0) ? (1.f - wy) * (1.f - wx) : 0.f;
        const float w01 = (vy0 && vx1) ? (1.f - wy) * wx         : 0.f;
        const float w10 = (vy1 && vx0) ? wy * (1.f - wx)         : 0.f;
        const float w11 = (vy1 && vx1) ? wy * wx                 : 0.f;
        const int i00 = cy0 * W + cx0;
        const int i01 = cy0 * W + cx1;
        const int i10 = cy1 * W + cx0;
        const int i11 = cy1 * W + cx1;
        #pragma unroll
        for (int c = 0; c < CIN; ++c) {
            const float* xc = xb + c * HW;
            float s = xc[i00] * w00;
            s = fmaf(xc[i01], w01, s);
            s = fmaf(xc[i10], w10, s);
            s = fmaf(xc[i11], w11, s);
            a0 = fmaf(s_dw[0 * 27 + c * 9 + k], s, a0);
            a1 = fmaf(s_dw[1 * 27 + c * 9 + k], s, a1);
            a2 = fmaf(s_dw[2 * 27 + c * 9 + k], s, a2);
        }
    }

    const int obase = b * (OOUT * HO * WO) + ho * WO + wo;
    __builtin_nontemporal_store(a0, out + obase);
    __builtin_nontemporal_store(a1, out + obase + HO * WO);
    __builtin_nontemporal_store(a2, out + obase + 2 * HO * WO);
}

extern "C" void kernel_launch(void* const* d_in, const int* in_sizes, int n_in,
                              void* d_out, int out_size, void* d_ws, size_t ws_size,
                              hipStream_t stream) {
    const float* x      = (const float*)d_in[0];
    const float* conv_w = (const float*)d_in[1];
    const float* conv_b = (const float*)d_in[2];
    const float* dcn_w  = (const float*)d_in[3];
    const float* dcn_b  = (const float*)d_in[4];
    float* out = (float*)d_out;

    const int total = BATCH * HO * WO;
    const size_t xt_bytes = (size_t)BATCH * HP * WP * sizeof(uint2);   // 19.3 MB
    const size_t need_bf  = xt_bytes + WPK_FLOATS * sizeof(float);

    if (ws_size >= need_bf) {
        uint2* xt = (uint2*)d_ws;
        float* wpk = (float*)((char*)d_ws + xt_bytes);
        dim3 pack_grid((HP * WP + 255) / 256, BATCH);
        pack_bf16_kernel<<<pack_grid, 256, 0, stream>>>(
            x, conv_w, conv_b, dcn_w, dcn_b, xt, wpk);
        deform_bf16_kernel<<<NWG2, 256, 0, stream>>>(x, xt, wpk, out);
    } else {
        deform_fused_kernel<<<(total + 255) / 256, 256, 0, stream>>>(
            x, conv_w, conv_b, dcn_w, dcn_b, out);
    }
}